// Round 4
// baseline (82.272 us; speedup 1.0000x reference)
//
#include <hip/hip_runtime.h>
#include <hip/hip_bf16.h>

#define H 128
#define STEPS 64
#define F_IN 33
#define R3H 384   // 3*H

// One fused kernel: each block (one step) recomputes gh itself from an
// XOR-swizzled LDS tile of W_hh (coalesced loads, conflict-free b128 LDS,
// no cross-thread reduction), then does gi + gates. Single dispatch.
__global__ __launch_bounds__(128) void Encoder_57380763074770_kernel(
    const float* __restrict__ x,        // [64,17]
    const int*   __restrict__ ip,       // [64,8]
    const int*   __restrict__ port,     // [64,2]
    const float* __restrict__ hidden,   // [128]
    const float* __restrict__ ip_emb,   // [256,1]
    const float* __restrict__ port_emb, // [70000,4]
    const float* __restrict__ W_ih,     // [384,33] row-major
    const float* __restrict__ W_hh,     // [384,128] row-major
    const float* __restrict__ b_ih,     // [384]
    const float* __restrict__ b_hh,     // [384]
    float* __restrict__ out)            // [64*128 + 128]
{
    // buf: first used as 96x32 float4 swizzled W_hh tile (3072 f4),
    // then reused as W_ih staging (3168 f4 = 50688 B).
    __shared__ float4 buf[3168];
    __shared__ float4 h0v[32];          // hidden as 32 float4 (16B aligned)
    __shared__ float  xi[F_IN + 3];

    const int tid = threadIdx.x;
    const int s   = blockIdx.x;         // step
    const int j   = tid;                // hidden unit

    // ---- stage xi = concat(x[s], ip_emb[ip[s]], port_emb[port[s]]) + h0 ----
    if (tid < 17) {
        xi[tid] = x[s * 17 + tid];
    } else if (tid < 25) {
        xi[tid] = ip_emb[ip[s * 8 + (tid - 17)]];
    } else if (tid < F_IN) {
        int c = tid - 25;               // 0..7
        xi[tid] = port_emb[port[s * 2 + (c >> 2)] * 4 + (c & 3)];
    }
    if (tid < 32) h0v[tid] = ((const float4*)hidden)[tid];

    // ---- gh rows j, j+128, j+256 via 4 swizzled chunks of 96 rows ----
    float ghv0 = 0.f, ghv1 = 0.f, ghv2 = 0.f;
    const float4* whh4 = (const float4*)W_hh;   // 12288 float4 total

    for (int c = 0; c < 4; ++c) {
        // stage chunk c (rows 96c..96c+95): coalesced global f4, swizzled LDS
        #pragma unroll
        for (int it = 0; it < 24; ++it) {
            const int g = tid + (it << 7);      // 0..3071 within chunk
            const int r = g >> 5;               // local row 0..95
            const int m = g & 31;               // col4
            buf[r * 32 + (m ^ (r & 31))] = whh4[c * 3072 + g];
        }
        __syncthreads();   // tile (and, on c==0, h0v/xi) visible

        const int lo = c * 96;
        // which of this thread's three rows live in this chunk?
        #pragma unroll
        for (int t = 0; t < 3; ++t) {
            const int lr = j + (t << 7) - lo;   // local row
            if (lr >= 0 && lr < 96) {
                const float4* trow = buf + lr * 32;
                const int key = lr & 31;
                float a = 0.f;
                #pragma unroll 8
                for (int i = 0; i < 32; ++i) {
                    const float4 w = trow[i ^ key];  // conflict-free b128
                    const float4 h = h0v[i];         // broadcast
                    a = fmaf(w.x, h.x, fmaf(w.y, h.y,
                        fmaf(w.z, h.z, fmaf(w.w, h.w, a))));
                }
                if (t == 0) ghv0 = a;
                else if (t == 1) ghv1 = a;
                else ghv2 = a;
            }
        }
        __syncthreads();   // all reads done before re-staging / wih overwrite
    }

    // ---- stage W_ih into buf (reuse), coalesced f4 ----
    const float4* wi4 = (const float4*)W_ih;    // 3168 float4
    #pragma unroll
    for (int it = 0; it < 25; ++it) {
        const int idx = tid + (it << 7);
        if (idx < 3168) buf[idx] = wi4[idx];
    }
    __syncthreads();

    // ---- gi = xi @ W_ih^T + b_ih (LDS, stride-33 conflict-free) ----
    const float* wihf = (const float*)buf;
    float gir = b_ih[j];
    float giz = b_ih[j + H];
    float gin = b_ih[j + 2 * H];
    const float* vr = wihf + j * F_IN;
    const float* vz = wihf + (j + H) * F_IN;
    const float* vn = wihf + (j + 2 * H) * F_IN;
    #pragma unroll
    for (int k = 0; k < F_IN; ++k) {
        const float xv = xi[k];
        gir = fmaf(xv, vr[k], gir);
        giz = fmaf(xv, vz[k], giz);
        gin = fmaf(xv, vn[k], gin);
    }

    const float ghr = ghv0 + b_hh[j];
    const float ghz = ghv1 + b_hh[j + H];
    const float ghn = ghv2 + b_hh[j + 2 * H];

    const float r = 1.0f / (1.0f + __expf(-(gir + ghr)));
    const float z = 1.0f / (1.0f + __expf(-(giz + ghz)));
    float a = gin + r * ghn;
    a = fminf(fmaxf(a, -15.0f), 15.0f);
    const float e2 = __expf(2.0f * a);
    const float n = (e2 - 1.0f) / (e2 + 1.0f);
    const float h0j = ((const float*)h0v)[j];
    const float o = (1.0f - z) * n + z * h0j;

    out[s * H + j] = o;
    if (s == STEPS - 1) out[STEPS * H + j] = o;   // new_hidden tail
}

extern "C" void kernel_launch(void* const* d_in, const int* in_sizes, int n_in,
                              void* d_out, int out_size, void* d_ws, size_t ws_size,
                              hipStream_t stream) {
    const float* x        = (const float*)d_in[0];
    const int*   ip       = (const int*)  d_in[1];
    const int*   port     = (const int*)  d_in[2];
    const float* hidden   = (const float*)d_in[3];
    const float* ip_emb   = (const float*)d_in[4];
    const float* port_emb = (const float*)d_in[5];
    const float* W_ih     = (const float*)d_in[6];
    const float* W_hh     = (const float*)d_in[7];
    const float* b_ih     = (const float*)d_in[8];
    const float* b_hh     = (const float*)d_in[9];
    float* out = (float*)d_out;

    Encoder_57380763074770_kernel<<<STEPS, H, 0, stream>>>(
        x, ip, port, hidden, ip_emb, port_emb, W_ih, W_hh, b_ih, b_hh, out);
}

// Round 5
// 77.349 us; speedup vs baseline: 1.0636x; 1.0636x over previous
//
#include <hip/hip_runtime.h>
#include <hip/hip_bf16.h>

#define H 128
#define STEPS 64
#define F_IN 33
#define R3H 384   // 3*H

// ---------- kernel 1: gh = W_hh @ h0 + b_hh, one wave per row ----------
// 384 independent wave-chains across 96 blocks: fully parallel, coalesced,
// total latency ~= one 128-MAC dot + reduce (~1 us).
__global__ __launch_bounds__(256) void gh_kernel(
    const float* __restrict__ hidden,   // [128]
    const float* __restrict__ W_hh,     // [384,128] row-major
    const float* __restrict__ b_hh,     // [384]
    float* __restrict__ gh)             // [384] (workspace)
{
    const int wave = threadIdx.x >> 6;            // 0..3
    const int lane = threadIdx.x & 63;
    const int row  = blockIdx.x * 4 + wave;       // 96 blocks * 4 = 384 rows
    const float* wrow = W_hh + (size_t)row * H;
    float p = wrow[lane] * hidden[lane] + wrow[lane + 64] * hidden[lane + 64];
    #pragma unroll
    for (int m = 32; m >= 1; m >>= 1) p += __shfl_xor(p, m, 64);
    if (lane == 0) gh[row] = p + b_hh[row];
}

// ---------- kernel 2: gi + gates, one block per step ----------
__global__ __launch_bounds__(128) void Encoder_57380763074770_kernel(
    const float* __restrict__ x,        // [64,17]
    const int*   __restrict__ ip,       // [64,8]
    const int*   __restrict__ port,     // [64,2]
    const float* __restrict__ hidden,   // [128]
    const float* __restrict__ ip_emb,   // [256,1]
    const float* __restrict__ port_emb, // [70000,4]
    const float* __restrict__ W_ih,     // [384,33] row-major
    const float* __restrict__ b_ih,     // [384]
    const float* __restrict__ gh,       // [384] precomputed (includes b_hh)
    float* __restrict__ out)            // [64*128 + 128]
{
    __shared__ float xi[F_IN];
    __shared__ float h0s[H];
    __shared__ float wih[R3H * F_IN];   // 12672 floats = 50688 B

    const int s   = blockIdx.x;         // step
    const int tid = threadIdx.x;

    // stage xi = concat(x[s], ip_emb[ip[s]], port_emb[port[s]])
    if (tid < 17) {
        xi[tid] = x[s * 17 + tid];
    } else if (tid < 25) {
        xi[tid] = ip_emb[ip[s * 8 + (tid - 17)]];
    } else if (tid < F_IN) {
        int c = tid - 25;               // 0..7
        xi[tid] = port_emb[port[s * 2 + (c >> 2)] * 4 + (c & 3)];
    }
    h0s[tid] = hidden[tid];

    // stage W_ih into LDS, coalesced float4 (12672 % 4 == 0); independent loads
    {
        const float4* w4 = (const float4*)W_ih;
        float4*       l4 = (float4*)wih;
        #pragma unroll
        for (int i = 0; i < (R3H * F_IN) / 4 / 128 + 1; ++i) {
            int idx = tid + i * 128;
            if (idx < (R3H * F_IN) / 4) l4[idx] = w4[idx];
        }
    }

    // pull gh rows (L2-hot, coalesced) while staging drains
    const int j = tid;
    const float ghr = gh[j];
    const float ghz = gh[j + H];
    const float ghn = gh[j + 2 * H];
    float gir = b_ih[j];
    float giz = b_ih[j + H];
    float gin = b_ih[j + 2 * H];

    __syncthreads();

    // gi = xi @ W_ih^T + b_ih (LDS, stride-33 is bank-conflict-free)
    const float* vr = wih + j * F_IN;
    const float* vz = wih + (j + H) * F_IN;
    const float* vn = wih + (j + 2 * H) * F_IN;
    #pragma unroll
    for (int k = 0; k < F_IN; ++k) {
        const float xv = xi[k];
        gir = fmaf(xv, vr[k], gir);
        giz = fmaf(xv, vz[k], giz);
        gin = fmaf(xv, vn[k], gin);
    }

    const float r = 1.0f / (1.0f + __expf(-(gir + ghr)));
    const float z = 1.0f / (1.0f + __expf(-(giz + ghz)));
    float a = gin + r * ghn;
    a = fminf(fmaxf(a, -15.0f), 15.0f);
    const float e2 = __expf(2.0f * a);
    const float n = (e2 - 1.0f) / (e2 + 1.0f);
    const float o = (1.0f - z) * n + z * h0s[j];

    out[s * H + j] = o;
    if (s == STEPS - 1) out[STEPS * H + j] = o;   // new_hidden tail
}

extern "C" void kernel_launch(void* const* d_in, const int* in_sizes, int n_in,
                              void* d_out, int out_size, void* d_ws, size_t ws_size,
                              hipStream_t stream) {
    const float* x        = (const float*)d_in[0];
    const int*   ip       = (const int*)  d_in[1];
    const int*   port     = (const int*)  d_in[2];
    const float* hidden   = (const float*)d_in[3];
    const float* ip_emb   = (const float*)d_in[4];
    const float* port_emb = (const float*)d_in[5];
    const float* W_ih     = (const float*)d_in[6];
    const float* W_hh     = (const float*)d_in[7];
    const float* b_ih     = (const float*)d_in[8];
    const float* b_hh     = (const float*)d_in[9];
    float* out = (float*)d_out;
    float* gh  = (float*)d_ws;          // 384 floats of scratch

    gh_kernel<<<96, 256, 0, stream>>>(hidden, W_hh, b_hh, gh);
    Encoder_57380763074770_kernel<<<STEPS, H, 0, stream>>>(
        x, ip, port, hidden, ip_emb, port_emb, W_ih, b_ih, gh, out);
}